// Round 7
// baseline (1538.688 us; speedup 1.0000x reference)
//
#include <hip/hip_runtime.h>
#include <stdint.h>
#include <math.h>

#define TTOK 8192
#define DDIM 1024
#define FDIM 4096
#define NEXP 8
#define NASG (TTOK*2)
#define MAXMT 32   // max 256-row tiles per expert (worst case: all tokens on one expert)

typedef __attribute__((ext_vector_type(8))) short bf16x8;
typedef __attribute__((ext_vector_type(4))) float f32x4;
typedef __attribute__((ext_vector_type(4))) float f4v;
typedef __attribute__((ext_vector_type(8))) unsigned short u16x8;

__device__ __forceinline__ unsigned short f2bf(float f) {
  union { float f; unsigned int u; } v; v.f = f;
  unsigned int u = v.u;
  u += 0x7fffu + ((u >> 16) & 1u);   // round-to-nearest-even
  return (unsigned short)(u >> 16);
}

__device__ __forceinline__ void gload16(const void* g, void* l) {
  __builtin_amdgcn_global_load_lds(
    (__attribute__((address_space(1))) unsigned int*)(uintptr_t)g,
    (__attribute__((address_space(3))) unsigned int*)(uintptr_t)l,
    16, 0, 0);
}

// ------ router: one wave per token, fp64 accumulate; also emits xb (bf16) ------
__global__ __launch_bounds__(256) void router_kernel(
    const float* __restrict__ x, const float* __restrict__ rw,
    const float* __restrict__ rb, int* __restrict__ topi,
    float* __restrict__ topw, int* __restrict__ counts,
    unsigned short* __restrict__ xb)
{
  int wave = threadIdx.x >> 6;
  int lane = threadIdx.x & 63;
  int t = blockIdx.x * 4 + wave;
  if (t >= TTOK) return;
  double acc[8];
#pragma unroll
  for (int e = 0; e < 8; e++) acc[e] = 0.0;
  const float* xr = x + (size_t)t * DDIM;
  unsigned short* xbr = xb + (size_t)t * DDIM;
  for (int d = lane; d < DDIM; d += 64) {
    float xf = xr[d];
    xbr[d] = f2bf(xf);
    double xv = (double)xf;
    const float* rwr = rw + (size_t)d * 8;
#pragma unroll
    for (int e = 0; e < 8; e++) acc[e] += xv * (double)rwr[e];
  }
#pragma unroll
  for (int e = 0; e < 8; e++) {
    for (int off = 32; off >= 1; off >>= 1)
      acc[e] += __shfl_xor(acc[e], off);
  }
  if (lane == 0) {
    float lg[8];
#pragma unroll
    for (int e = 0; e < 8; e++) lg[e] = (float)acc[e] + rb[e];
    int i0 = 0;
    for (int e = 1; e < 8; e++) if (lg[e] > lg[i0]) i0 = e;   // ties -> lowest idx
    int i1 = -1;
    for (int e = 0; e < 8; e++) {
      if (e == i0) continue;
      if (i1 < 0 || lg[e] > lg[i1]) i1 = e;
    }
    double z = exp((double)lg[i1] - (double)lg[i0]);
    float w0 = (float)(1.0 / (1.0 + z));
    topi[t*2]   = i0;  topi[t*2+1] = i1;
    topw[t*2]   = w0;  topw[t*2+1] = 1.0f - w0;
    atomicAdd(&counts[i0], 1);
    atomicAdd(&counts[i1], 1);
  }
}

// ------ deterministic stable counting sort (single block; includes scan) ------
__global__ __launch_bounds__(256) void permbuild_kernel(
    const int* __restrict__ topi, const int* __restrict__ counts,
    int* __restrict__ offsets, int* __restrict__ perm, int* __restrict__ islot)
{
  __shared__ int hist[256 * 8];
  __shared__ int offs[NEXP + 1];
  int tid = threadIdx.x;
  if (tid == 0) {
    int s = 0;
    for (int e = 0; e < 8; e++) { offs[e] = s; s += counts[e]; }
    offs[8] = s;
    for (int e = 0; e <= 8; e++) offsets[e] = offs[e];
  }
  int cnt[8];
#pragma unroll
  for (int e = 0; e < 8; e++) cnt[e] = 0;
  int base = tid * 64;
  for (int i = 0; i < 64; i++) cnt[topi[base + i]]++;
#pragma unroll
  for (int e = 0; e < 8; e++) hist[tid*8 + e] = cnt[e];
  __syncthreads();
  if (tid < 8) {
    int s = 0;
    for (int th = 0; th < 256; th++) { int v = hist[th*8 + tid]; hist[th*8 + tid] = s; s += v; }
  }
  __syncthreads();
  int pos[8];
#pragma unroll
  for (int e = 0; e < 8; e++) pos[e] = offs[e] + hist[tid*8 + e];
  for (int i = 0; i < 64; i++) {
    int a = base + i;
    int e = topi[a];
    int p = pos[e]++;
    perm[p] = a >> 1;
    islot[a] = p;
  }
}

// ------- batched transpose + convert: [E][R][C] f32 -> [E][C][R] bf16 --------
__global__ __launch_bounds__(256) void transpose_kernel(
    const float* __restrict__ w, unsigned short* __restrict__ wt, int R, int C)
{
  __shared__ float tile[64][65];
  int tilesPerRow = C >> 6;
  int tilesPerMat = (R >> 6) * tilesPerRow;
  int b = blockIdx.x;
  int e = b / tilesPerMat;
  int rem = b - e * tilesPerMat;
  int tr = rem / tilesPerRow;
  int tc = rem - tr * tilesPerRow;
  int tid = threadIdx.x;
  size_t ibase = (size_t)e*R*C + ((size_t)tr*64)*C + (size_t)tc*64;
#pragma unroll
  for (int i = 0; i < 16; i++) {
    int idx = tid + i*256;
    int r = idx >> 6, c = idx & 63;
    tile[r][c] = w[ibase + (size_t)r*C + c];
  }
  __syncthreads();
  size_t obase = (size_t)e*R*C + ((size_t)tc*64)*R + (size_t)tr*64;
#pragma unroll
  for (int i = 0; i < 16; i++) {
    int idx = tid + i*256;
    int r = idx >> 6, c = idx & 63;
    wt[obase + (size_t)r*R + c] = f2bf(tile[c][r]);
  }
}

// ========== 256x256 grouped GEMM: zero-VALU inner loop (asm ds_read) ==========
// LDS 128KB = 8 regions of 16KB: region = buf*4 + {A0=0, A1=1, B0=2, B1=3}.
// A half-1 at +16384; B0 at +32768; B1 at +49152 (buf1: +65536 on all).
// Swizzle byte ^= (row&7)<<4 folded into per-thread base regs; all ds_read via
// base + 16-bit offset immediates. Counted lgkmcnt/vmcnt, 4 barriers/K-tile.
// A rows are PERM-GATHERED: each of the 4 row-groups (r0, +64, +128, +192)
// needs its OWN pointer with its own perm lookup (round-6 bug: +rowOff on A).

#define DS_RD(D, B, O) asm volatile("ds_read_b128 %0, %1 offset:%c2" : "=v"(D) : "v"(B), "i"(O))

#define RDA(FR, BV, MH) \
  DS_RD(FR[0][0], aA0_b##BV, (MH)*16384 + 0);    \
  DS_RD(FR[0][1], aA1_b##BV, (MH)*16384 + 0);    \
  DS_RD(FR[1][0], aA0_b##BV, (MH)*16384 + 2048); \
  DS_RD(FR[1][1], aA1_b##BV, (MH)*16384 + 2048); \
  DS_RD(FR[2][0], aA0_b##BV, (MH)*16384 + 4096); \
  DS_RD(FR[2][1], aA1_b##BV, (MH)*16384 + 4096); \
  DS_RD(FR[3][0], aA0_b##BV, (MH)*16384 + 6144); \
  DS_RD(FR[3][1], aA1_b##BV, (MH)*16384 + 6144);

#define RDB(FR, BV, NH) \
  DS_RD(FR[0][0], aB0_b##BV, 32768 + (NH)*16384 + 0);    \
  DS_RD(FR[0][1], aB1_b##BV, 32768 + (NH)*16384 + 0);    \
  DS_RD(FR[1][0], aB0_b##BV, 32768 + (NH)*16384 + 2048); \
  DS_RD(FR[1][1], aB1_b##BV, 32768 + (NH)*16384 + 2048);

// A stages: two independent gathered row-group pointers per half
#define STAGE_A0(BV) { gload16(pA0a, ldsb + ((BV)*4+0)*16384 + dst0); \
                       gload16(pA0b, ldsb + ((BV)*4+0)*16384 + dst1); pA0a += 128; pA0b += 128; }
#define STAGE_A1(BV) { gload16(pA1a, ldsb + ((BV)*4+1)*16384 + dst0); \
                       gload16(pA1b, ldsb + ((BV)*4+1)*16384 + dst1); pA1a += 128; pA1b += 128; }
// B stages: weights are contiguous in N -> second group via +64-row offset
#define STAGE_B0(BV) { gload16(pB0, ldsb + ((BV)*4+2)*16384 + dst0); \
                       gload16(pB0 + rowOffB, ldsb + ((BV)*4+2)*16384 + dst1); pB0 += 128; }
#define STAGE_B1(BV) { gload16(pB1, ldsb + ((BV)*4+3)*16384 + dst0); \
                       gload16(pB1 + rowOffB, ldsb + ((BV)*4+3)*16384 + dst1); pB1 += 128; }

#define MFMA_Q(MH, NH, A_, B_)                                               \
    __builtin_amdgcn_s_setprio(1);                                           \
    _Pragma("unroll") for (int ks = 0; ks < 2; ks++)                         \
      _Pragma("unroll") for (int mi = 0; mi < 4; mi++)                       \
        _Pragma("unroll") for (int ni = 0; ni < 2; ni++)                     \
          acc[(MH)*4+mi][(NH)*2+ni] = __builtin_amdgcn_mfma_f32_16x16x32_bf16( \
              A_[mi][ks], B_[ni][ks], acc[(MH)*4+mi][(NH)*2+ni], 0, 0, 0);   \
    __builtin_amdgcn_s_setprio(0);

// BV: current buffer (literal), BN: next buffer, STG: stage kt+2?, VM: vmcnt
// literal string, RDN: read next tile's A0/B0 fragments at P4?
#define KTILE(BV, BN, STG, VM, RDN)                                          \
  {                                                                          \
    /* P1: Q00; read B1 */                                                   \
    RDB(bfr1, BV, 1)                                                         \
    __builtin_amdgcn_s_barrier();                                            \
    asm volatile("s_waitcnt lgkmcnt(4)");                                    \
    __builtin_amdgcn_sched_barrier(0);                                       \
    MFMA_Q(0,0, afr0, bfr0)                                                  \
    __builtin_amdgcn_sched_barrier(0);                                       \
    /* P2: Q01; read A1; stage A0,B0(kt+2) */                                \
    RDA(afr1, BV, 1)                                                         \
    if (STG) { STAGE_A0(BV); STAGE_B0(BV); }                                 \
    __builtin_amdgcn_s_barrier();                                            \
    asm volatile("s_waitcnt lgkmcnt(8)");                                    \
    __builtin_amdgcn_sched_barrier(0);                                       \
    MFMA_Q(0,1, afr0, bfr1)                                                  \
    __builtin_amdgcn_sched_barrier(0);                                       \
    /* P3: Q10; stage B1(kt+2) */                                            \
    if (STG) { STAGE_B1(BV); }                                               \
    __builtin_amdgcn_s_barrier();                                            \
    asm volatile("s_waitcnt lgkmcnt(0)");                                    \
    __builtin_amdgcn_sched_barrier(0);                                       \
    MFMA_Q(1,0, afr1, bfr0)                                                  \
    __builtin_amdgcn_sched_barrier(0);                                       \
    /* P4: Q11; stage A1(kt+2); counted vmcnt; read next A0,B0 */            \
    if (STG) { STAGE_A1(BV); }                                               \
    asm volatile("s_waitcnt vmcnt(" VM ")");                                 \
    __builtin_amdgcn_s_barrier();                                            \
    if (RDN) { RDA(afr0, BN, 0) RDB(bfr0, BN, 0) }                           \
    __builtin_amdgcn_sched_barrier(0);                                       \
    MFMA_Q(1,1, afr1, bfr1)                                                  \
    __builtin_amdgcn_sched_barrier(0);                                       \
  }

template<int KDIM, int NDIM, bool GELU>
__global__ __launch_bounds__(512, 2) void gemm256(
    const unsigned short* __restrict__ Asrc,
    const unsigned short* __restrict__ Bsrc,
    const float* __restrict__ bias,
    const int* __restrict__ perm,
    const int* __restrict__ offsets,
    void* __restrict__ Cout)
{
  constexpr int KT = KDIM / 64;
  constexpr int NT = NDIM / 256;
  int b = blockIdx.x;
  int e = b / (MAXMT * NT);
  int rem = b - e * (MAXMT * NT);
  int rt = rem / NT;
  int nt = rem - rt * NT;
  int off = offsets[e];
  int n_e = offsets[e+1] - off;
  if (rt * 256 >= n_e) return;

  __shared__ __align__(16) unsigned short lds[2*2*2*8192];   // 128 KiB
  char* ldsb = (char*)lds;

  int tid = threadIdx.x;
  int lane = tid & 63;
  int wid = tid >> 6;
  int wr = wid >> 2;          // 0..1  (M strips)
  int wc = wid & 3;           // 0..3  (N strips)
  int rA  = wr*64 + (lane & 15);
  int rB  = wc*32 + (lane & 15);
  int tb0 = (lane >> 4) * 16;

  // ---- per-thread LDS read base registers (swizzle folded in) ----
  uint32_t lb = (uint32_t)(uintptr_t)ldsb;   // LDS byte offset of array base
  int xa = (rA & 7) << 4;
  int xbv = (rB & 7) << 4;
  uint32_t aA0_b0 = lb + (uint32_t)(rA*128 + (tb0 ^ xa));
  uint32_t aA1_b0 = lb + (uint32_t)(rA*128 + ((64 + tb0) ^ xa));
  uint32_t aB0_b0 = lb + (uint32_t)(rB*128 + (tb0 ^ xbv));
  uint32_t aB1_b0 = lb + (uint32_t)(rB*128 + ((64 + tb0) ^ xbv));
  uint32_t aA0_b1 = aA0_b0 + 65536;
  uint32_t aA1_b1 = aA1_b0 + 65536;
  uint32_t aB0_b1 = aB0_b0 + 65536;
  uint32_t aB1_b1 = aB1_b0 + 65536;

  // ---- per-thread stage pointers (inverse-swizzled global source) ----
  int r0 = tid >> 3;                 // 0..63
  int kc = (tid & 7) ^ (r0 & 7);     // inverse-swizzled k-chunk
  const char *pA0a, *pA0b, *pA1a, *pA1b, *pB0, *pB1;
  {
    int g0 = off + rt*256 +   0 + r0; if (g0 > NASG-1) g0 = NASG-1;
    int g1 = off + rt*256 +  64 + r0; if (g1 > NASG-1) g1 = NASG-1;
    int g2 = off + rt*256 + 128 + r0; if (g2 > NASG-1) g2 = NASG-1;
    int g3 = off + rt*256 + 192 + r0; if (g3 > NASG-1) g3 = NASG-1;
    size_t a0 = GELU ? (size_t)perm[g0] : (size_t)g0;
    size_t a1 = GELU ? (size_t)perm[g1] : (size_t)g1;
    size_t a2 = GELU ? (size_t)perm[g2] : (size_t)g2;
    size_t a3 = GELU ? (size_t)perm[g3] : (size_t)g3;
    pA0a = (const char*)Asrc + (a0 * KDIM + (size_t)kc*8) * 2;
    pA0b = (const char*)Asrc + (a1 * KDIM + (size_t)kc*8) * 2;
    pA1a = (const char*)Asrc + (a2 * KDIM + (size_t)kc*8) * 2;
    pA1b = (const char*)Asrc + (a3 * KDIM + (size_t)kc*8) * 2;
    int c0 = nt*256 + r0;
    int c1 = nt*256 + 128 + r0;
    pB0 = (const char*)Bsrc + (((size_t)e*NDIM + c0) * KDIM + (size_t)kc*8) * 2;
    pB1 = (const char*)Bsrc + (((size_t)e*NDIM + c1) * KDIM + (size_t)kc*8) * 2;
  }
  const size_t rowOffB = (size_t)64 * KDIM * 2;   // +64 N-rows (contiguous weights)
  int dst0 = tid*16;
  int dst1 = tid*16 + 8192;

  f32x4 acc[8][4];
#pragma unroll
  for (int m = 0; m < 8; m++)
#pragma unroll
    for (int n = 0; n < 4; n++) acc[m][n] = (f32x4){0.f,0.f,0.f,0.f};

  bf16x8 afr0[4][2], afr1[4][2];   // A half-0 / half-1 fragments
  bf16x8 bfr0[2][2], bfr1[2][2];   // B half-0 / half-1 fragments

  // prologue: stage kt0 -> buf0, kt1 -> buf1; retire kt0; pre-read A0,B0
  STAGE_A0(0); STAGE_B0(0); STAGE_B1(0); STAGE_A1(0);
  STAGE_A0(1); STAGE_B0(1); STAGE_B1(1); STAGE_A1(1);
  asm volatile("s_waitcnt vmcnt(8)");
  __builtin_amdgcn_s_barrier();
  RDA(afr0, 0, 0) RDB(bfr0, 0, 0)
  __builtin_amdgcn_sched_barrier(0);

#pragma unroll 1
  for (int kt = 0; kt < KT-2; kt += 2) {
    KTILE(0, 1, 1, "8", 1)
    KTILE(1, 0, 1, "8", 1)
  }
  // drain: tiles KT-2 (buf0) and KT-1 (buf1), no staging
  KTILE(0, 1, 0, "0", 1)
  KTILE(1, 0, 0, "0", 0)

  // epilogue
  int rq = (lane >> 4) * 4;
  int lc = lane & 15;
  if (GELU) {
    unsigned short* H = (unsigned short*)Cout;
#pragma unroll
    for (int mh = 0; mh < 2; mh++)
#pragma unroll
      for (int mi = 0; mi < 4; mi++)
#pragma unroll
        for (int j = 0; j < 4; j++) {
          int sl = rt*256 + mh*128 + wr*64 + mi*16 + rq + j;
          if (sl < n_e) {
            size_t hrow = (size_t)(off + sl) * NDIM;
#pragma unroll
            for (int nh = 0; nh < 2; nh++)
#pragma unroll
              for (int ni = 0; ni < 2; ni++) {
                int col = nt*256 + nh*128 + wc*32 + ni*16 + lc;
                float v = acc[mh*4+mi][nh*2+ni][j] + bias[e*NDIM + col];
                float g = 0.5f * v * (1.0f + erff(v * 0.70710678118654752f));
                H[hrow + col] = f2bf(g);
              }
          }
        }
  } else {
    float* Y = (float*)Cout;
#pragma unroll
    for (int mh = 0; mh < 2; mh++)
#pragma unroll
      for (int mi = 0; mi < 4; mi++)
#pragma unroll
        for (int j = 0; j < 4; j++) {
          int sl = rt*256 + mh*128 + wr*64 + mi*16 + rq + j;
          if (sl < n_e) {
            size_t yrow = (size_t)(off + sl) * NDIM;
#pragma unroll
            for (int nh = 0; nh < 2; nh++)
#pragma unroll
              for (int ni = 0; ni < 2; ni++) {
                int col = nt*256 + nh*128 + wc*32 + ni*16 + lc;
                Y[yrow + col] = acc[mh*4+mi][nh*2+ni][j];
              }
          }
        }
  }
}

// ---------- combine: out[t] = sum_k w_k * (Y[slot_k] + b2[e_k]) ----------
__global__ __launch_bounds__(256) void combine_kernel(
    const float* __restrict__ Y, const float* __restrict__ b2,
    const int* __restrict__ topi, const float* __restrict__ topw,
    const int* __restrict__ islot, float* __restrict__ out)
{
  int t = blockIdx.x;
  int s0 = islot[t*2], s1 = islot[t*2+1];
  int e0 = topi[t*2],  e1 = topi[t*2+1];
  float w0 = topw[t*2], w1 = topw[t*2+1];
  int d = threadIdx.x * 4;
  f4v y0 = *(const f4v*)(Y + (size_t)s0*DDIM + d);
  f4v y1 = *(const f4v*)(Y + (size_t)s1*DDIM + d);
  f4v c0 = *(const f4v*)(b2 + (size_t)e0*DDIM + d);
  f4v c1 = *(const f4v*)(b2 + (size_t)e1*DDIM + d);
  f4v o = w0*(y0+c0) + w1*(y1+c1);
  *(f4v*)(out + (size_t)t*DDIM + d) = o;
}

extern "C" void kernel_launch(void* const* d_in, const int* in_sizes, int n_in,
                              void* d_out, int out_size, void* d_ws, size_t ws_size,
                              hipStream_t stream) {
  const float* x  = (const float*)d_in[0];
  const float* w1 = (const float*)d_in[1];
  const float* b1 = (const float*)d_in[2];
  const float* w2 = (const float*)d_in[3];
  const float* b2 = (const float*)d_in[4];
  const float* rw = (const float*)d_in[5];
  const float* rb = (const float*)d_in[6];
  float* out = (float*)d_out;

  char* p = (char*)d_ws;
  size_t o = 0;
  auto take = [&](size_t bytes) -> void* {
    void* r = p + o;
    o = (o + bytes + 255) & ~(size_t)255;
    return r;
  };
  int*            counts  = (int*)take(NEXP * 4);
  int*            offsets = (int*)take((NEXP + 1) * 4);
  int*            topi    = (int*)take((size_t)NASG * 4);
  float*          topw    = (float*)take((size_t)NASG * 4);
  int*            perm    = (int*)take((size_t)NASG * 4);
  int*            islot   = (int*)take((size_t)NASG * 4);
  unsigned short* w1t     = (unsigned short*)take((size_t)NEXP * FDIM * DDIM * 2);
  unsigned short* xb      = (unsigned short*)take((size_t)TTOK * DDIM * 2);
  unsigned short* w2t     = (unsigned short*)take((size_t)NEXP * DDIM * FDIM * 2);
  unsigned short* H       = (unsigned short*)take((size_t)NASG * FDIM * 2);
  // Y aliases w1t (dead after gemm1): NASG*DDIM*4 = 64 MiB = exactly w1t's size
  float*          Y       = (float*)w1t;

  if (o > ws_size) {   // workspace insufficient: fail visibly (zeros)
    hipMemsetAsync(d_out, 0, (size_t)out_size * 4, stream);
    return;
  }

  hipMemsetAsync(counts, 0, NEXP * 4, stream);

  router_kernel<<<TTOK/4, 256, 0, stream>>>(x, rw, rb, topi, topw, counts, xb);
  permbuild_kernel<<<1, 256, 0, stream>>>(topi, counts, offsets, perm, islot);
  transpose_kernel<<<NEXP*(DDIM/64)*(FDIM/64), 256, 0, stream>>>(w1, w1t, DDIM, FDIM);
  transpose_kernel<<<NEXP*(FDIM/64)*(DDIM/64), 256, 0, stream>>>(w2, w2t, FDIM, DDIM);
  gemm256<DDIM, FDIM, true ><<<NEXP*MAXMT*(FDIM/256), 512, 0, stream>>>(xb, w1t, b1, perm, offsets, (void*)H);
  gemm256<FDIM, DDIM, false><<<NEXP*MAXMT*(DDIM/256), 512, 0, stream>>>(H, w2t, nullptr, nullptr, offsets, (void*)Y);
  combine_kernel<<<TTOK, 256, 0, stream>>>(Y, b2, topi, topw, islot, out);
}

// Round 8
// 1499.599 us; speedup vs baseline: 1.0261x; 1.0261x over previous
//
#include <hip/hip_runtime.h>
#include <stdint.h>
#include <math.h>

#define TTOK 8192
#define DDIM 1024
#define FDIM 4096
#define NEXP 8
#define NASG (TTOK*2)
#define MAXMT 32   // max 256-row tiles per expert (worst case: all tokens on one expert)

typedef __attribute__((ext_vector_type(8))) short bf16x8;
typedef __attribute__((ext_vector_type(4))) float f32x4;
typedef __attribute__((ext_vector_type(4))) float f4v;
typedef __attribute__((ext_vector_type(8))) unsigned short u16x8;

__device__ __forceinline__ unsigned short f2bf(float f) {
  union { float f; unsigned int u; } v; v.f = f;
  unsigned int u = v.u;
  u += 0x7fffu + ((u >> 16) & 1u);   // round-to-nearest-even
  return (unsigned short)(u >> 16);
}

__device__ __forceinline__ void gload16(const void* g, void* l) {
  __builtin_amdgcn_global_load_lds(
    (__attribute__((address_space(1))) unsigned int*)(uintptr_t)g,
    (__attribute__((address_space(3))) unsigned int*)(uintptr_t)l,
    16, 0, 0);
}

// ------ router: one wave per token, fp64 accumulate; also emits xb (bf16) ------
__global__ __launch_bounds__(256) void router_kernel(
    const float* __restrict__ x, const float* __restrict__ rw,
    const float* __restrict__ rb, int* __restrict__ topi,
    float* __restrict__ topw, int* __restrict__ counts,
    unsigned short* __restrict__ xb)
{
  int wave = threadIdx.x >> 6;
  int lane = threadIdx.x & 63;
  int t = blockIdx.x * 4 + wave;
  if (t >= TTOK) return;
  double acc[8];
#pragma unroll
  for (int e = 0; e < 8; e++) acc[e] = 0.0;
  const float* xr = x + (size_t)t * DDIM;
  unsigned short* xbr = xb + (size_t)t * DDIM;
  for (int d = lane; d < DDIM; d += 64) {
    float xf = xr[d];
    xbr[d] = f2bf(xf);
    double xv = (double)xf;
    const float* rwr = rw + (size_t)d * 8;
#pragma unroll
    for (int e = 0; e < 8; e++) acc[e] += xv * (double)rwr[e];
  }
#pragma unroll
  for (int e = 0; e < 8; e++) {
    for (int off = 32; off >= 1; off >>= 1)
      acc[e] += __shfl_xor(acc[e], off);
  }
  if (lane == 0) {
    float lg[8];
#pragma unroll
    for (int e = 0; e < 8; e++) lg[e] = (float)acc[e] + rb[e];
    int i0 = 0;
    for (int e = 1; e < 8; e++) if (lg[e] > lg[i0]) i0 = e;   // ties -> lowest idx
    int i1 = -1;
    for (int e = 0; e < 8; e++) {
      if (e == i0) continue;
      if (i1 < 0 || lg[e] > lg[i1]) i1 = e;
    }
    double z = exp((double)lg[i1] - (double)lg[i0]);
    float w0 = (float)(1.0 / (1.0 + z));
    topi[t*2]   = i0;  topi[t*2+1] = i1;
    topw[t*2]   = w0;  topw[t*2+1] = 1.0f - w0;
    atomicAdd(&counts[i0], 1);
    atomicAdd(&counts[i1], 1);
  }
}

// ------ deterministic stable counting sort (single block; includes scan) ------
__global__ __launch_bounds__(256) void permbuild_kernel(
    const int* __restrict__ topi, const int* __restrict__ counts,
    int* __restrict__ offsets, int* __restrict__ perm, int* __restrict__ islot)
{
  __shared__ int hist[256 * 8];
  __shared__ int offs[NEXP + 1];
  int tid = threadIdx.x;
  if (tid == 0) {
    int s = 0;
    for (int e = 0; e < 8; e++) { offs[e] = s; s += counts[e]; }
    offs[8] = s;
    for (int e = 0; e <= 8; e++) offsets[e] = offs[e];
  }
  int cnt[8];
#pragma unroll
  for (int e = 0; e < 8; e++) cnt[e] = 0;
  int base = tid * 64;
  for (int i = 0; i < 64; i++) cnt[topi[base + i]]++;
#pragma unroll
  for (int e = 0; e < 8; e++) hist[tid*8 + e] = cnt[e];
  __syncthreads();
  if (tid < 8) {
    int s = 0;
    for (int th = 0; th < 256; th++) { int v = hist[th*8 + tid]; hist[th*8 + tid] = s; s += v; }
  }
  __syncthreads();
  int pos[8];
#pragma unroll
  for (int e = 0; e < 8; e++) pos[e] = offs[e] + hist[tid*8 + e];
  for (int i = 0; i < 64; i++) {
    int a = base + i;
    int e = topi[a];
    int p = pos[e]++;
    perm[p] = a >> 1;
    islot[a] = p;
  }
}

// ------- batched transpose + convert: [E][R][C] f32 -> [E][C][R] bf16 --------
__global__ __launch_bounds__(256) void transpose_kernel(
    const float* __restrict__ w, unsigned short* __restrict__ wt, int R, int C)
{
  __shared__ float tile[64][65];
  int tilesPerRow = C >> 6;
  int tilesPerMat = (R >> 6) * tilesPerRow;
  int b = blockIdx.x;
  int e = b / tilesPerMat;
  int rem = b - e * tilesPerMat;
  int tr = rem / tilesPerRow;
  int tc = rem - tr * tilesPerRow;
  int tid = threadIdx.x;
  size_t ibase = (size_t)e*R*C + ((size_t)tr*64)*C + (size_t)tc*64;
#pragma unroll
  for (int i = 0; i < 16; i++) {
    int idx = tid + i*256;
    int r = idx >> 6, c = idx & 63;
    tile[r][c] = w[ibase + (size_t)r*C + c];
  }
  __syncthreads();
  size_t obase = (size_t)e*R*C + ((size_t)tc*64)*R + (size_t)tr*64;
#pragma unroll
  for (int i = 0; i < 16; i++) {
    int idx = tid + i*256;
    int r = idx >> 6, c = idx & 63;
    wt[obase + (size_t)r*R + c] = f2bf(tile[c][r]);
  }
}

// ========== 256x256 grouped GEMM: hoisted-address 4-phase pipeline ==========
// LDS 128KB = 8 x 16KB regions: A regions at (half*2+buf)*16KB; B at +64KB same.
// Per-thread read bases (swizzle XOR folded, per-ks constants) + literal region
// offsets -> ds_read_b128 with offset: immediates, no per-read VALU, compiler
// keeps dependency tracking (no manual lgkmcnt). Round-4 phase/barrier/vmcnt
// structure verbatim; loop unrolled x2 so buf is a compile-time literal.

#define READ_AF(DST, MH, BUF)                                                \
  { const char* Ab_ = ldsA + ((MH)*2+(BUF))*16384;                           \
    _Pragma("unroll") for (int mi = 0; mi < 4; mi++) {                       \
      DST[mi][0] = *(const bf16x8*)(Ab_ + mi*2048 + aks0);                   \
      DST[mi][1] = *(const bf16x8*)(Ab_ + mi*2048 + aks1); } }

#define READ_BF(DST, NH, BUF)                                                \
  { const char* Bb_ = ldsB + ((NH)*2+(BUF))*16384;                           \
    _Pragma("unroll") for (int ni = 0; ni < 2; ni++) {                       \
      DST[ni][0] = *(const bf16x8*)(Bb_ + ni*2048 + bks0);                   \
      DST[ni][1] = *(const bf16x8*)(Bb_ + ni*2048 + bks1); } }

#define STAGE_A(H_, T_, BB_) { char* d_ = ldsA + ((H_)*2+(BB_))*16384;       \
  gload16(srcA[H_][0] + (size_t)(T_)*128, d_ + dst0);                        \
  gload16(srcA[H_][1] + (size_t)(T_)*128, d_ + dst1); }

#define STAGE_B(H_, T_, BB_) { char* d_ = ldsB + ((H_)*2+(BB_))*16384;       \
  gload16(srcB[H_][0] + (size_t)(T_)*128, d_ + dst0);                        \
  gload16(srcB[H_][1] + (size_t)(T_)*128, d_ + dst1); }

#define MFMA_Q(MH, NH, A_, B_)                                               \
    __builtin_amdgcn_s_setprio(1);                                           \
    _Pragma("unroll") for (int ks = 0; ks < 2; ks++)                         \
      _Pragma("unroll") for (int mi = 0; mi < 4; mi++)                       \
        _Pragma("unroll") for (int ni = 0; ni < 2; ni++)                     \
          acc[(MH)*4+mi][(NH)*2+ni] = __builtin_amdgcn_mfma_f32_16x16x32_bf16( \
              A_[mi][ks], B_[ni][ks], acc[(MH)*4+mi][(NH)*2+ni], 0, 0, 0);   \
    __builtin_amdgcn_s_setprio(0);

// BV: current buf (literal), BN: next buf, STG: stage kt+2?, VM: vmcnt literal,
// RDN: read next tile's A0/B0 fragments at P4?
#define KTILE(KT_, BV, BN, STG, VM, RDN)                                     \
  {                                                                          \
    /* P1: Q(0,0); read B1(kt) ahead */                                      \
    READ_BF(bfr1, 1, BV)                                                     \
    __builtin_amdgcn_sched_barrier(0);                                       \
    __builtin_amdgcn_s_barrier();                                            \
    MFMA_Q(0,0, afr0, bfr0)                                                  \
    /* P2: Q(0,1); read A1(kt) ahead; stage A0,B0(kt+2) */                   \
    READ_AF(afr1, 1, BV)                                                     \
    if (STG) { STAGE_A(0, (KT_)+2, BV); STAGE_B(0, (KT_)+2, BV); }           \
    __builtin_amdgcn_sched_barrier(0);                                       \
    __builtin_amdgcn_s_barrier();                                            \
    MFMA_Q(0,1, afr0, bfr1)                                                  \
    /* P3: Q(1,0); stage B1(kt+2) */                                         \
    if (STG) { STAGE_B(1, (KT_)+2, BV); }                                    \
    __builtin_amdgcn_sched_barrier(0);                                       \
    __builtin_amdgcn_s_barrier();                                            \
    MFMA_Q(1,0, afr1, bfr0)                                                  \
    /* P4: Q(1,1); stage A1(kt+2); vmcnt; barrier; read-ahead A0,B0(kt+1) */ \
    if (STG) { STAGE_A(1, (KT_)+2, BV); }                                    \
    __builtin_amdgcn_sched_barrier(0);                                       \
    asm volatile("s_waitcnt vmcnt(" VM ")" ::: "memory");                    \
    __builtin_amdgcn_s_barrier();                                            \
    if (RDN) {                                                               \
      READ_AF(afr0, 0, BN)                                                   \
      READ_BF(bfr0, 0, BN)                                                   \
      __builtin_amdgcn_sched_barrier(0);                                     \
    }                                                                        \
    MFMA_Q(1,1, afr1, bfr1)                                                  \
  }

template<int KDIM, int NDIM, bool GELU>
__global__ __launch_bounds__(512, 2) void gemm256(
    const unsigned short* __restrict__ Asrc,
    const unsigned short* __restrict__ Bsrc,
    const float* __restrict__ bias,
    const int* __restrict__ perm,
    const int* __restrict__ offsets,
    void* __restrict__ Cout)
{
  constexpr int KT = KDIM / 64;
  constexpr int NT = NDIM / 256;
  int b = blockIdx.x;
  int e = b / (MAXMT * NT);
  int rem = b - e * (MAXMT * NT);
  int rt = rem / NT;
  int nt = rem - rt * NT;
  int off = offsets[e];
  int n_e = offsets[e+1] - off;
  if (rt * 256 >= n_e) return;

  __shared__ __align__(16) unsigned short lds[2*2*2*8192];   // 128 KiB
  char* ldsA = (char*)lds;            // 4 A regions (half*2+buf)*16KB
  char* ldsB = (char*)lds + 65536;    // 4 B regions

  int tid = threadIdx.x;
  int lane = tid & 63;
  int wid = tid >> 6;
  int wr = wid >> 2;          // 0..1  (M strips)
  int wc = wid & 3;           // 0..3  (N strips)
  int rA  = wr*64 + (lane & 15);
  int rB  = wc*32 + (lane & 15);
  int tb0 = (lane >> 4) * 16;

  // per-thread read bases: swizzle XOR is per-thread constant ((row&7) is
  // invariant across mi/ni since fragment row stride 16 = 0 mod 8)
  int xa  = (rA & 7) << 4;
  int xbw = (rB & 7) << 4;
  int aks0 = rA*128 + ( tb0       ^ xa);
  int aks1 = rA*128 + ((64 + tb0) ^ xa);
  int bks0 = rB*128 + ( tb0       ^ xbw);
  int bks1 = rB*128 + ((64 + tb0) ^ xbw);

  // per-thread stage pointers (inverse-swizzled global source, linear LDS dest)
  const char* srcA[2][2];
  const char* srcB[2][2];
#pragma unroll
  for (int h = 0; h < 2; h++) {
#pragma unroll
    for (int i = 0; i < 2; i++) {
      int slot = tid + i*512;
      int r = slot >> 3;
      int kc = (slot & 7) ^ (r & 7);
      int g = off + rt*256 + h*128 + r;
      if (g > NASG-1) g = NASG-1;
      size_t arow = GELU ? (size_t)perm[g] : (size_t)g;
      srcA[h][i] = (const char*)Asrc + (arow * KDIM + (size_t)kc*8) * 2;
      int col = nt*256 + h*128 + r;
      srcB[h][i] = (const char*)Bsrc + (((size_t)e*NDIM + col) * KDIM + (size_t)kc*8) * 2;
    }
  }
  int dst0 = tid*16;
  int dst1 = tid*16 + 8192;

  f32x4 acc[8][4];
#pragma unroll
  for (int m = 0; m < 8; m++)
#pragma unroll
    for (int n = 0; n < 4; n++) acc[m][n] = (f32x4){0.f,0.f,0.f,0.f};

  bf16x8 afr0[4][2], afr1[4][2];   // A half-0 / half-1 fragments
  bf16x8 bfr0[2][2], bfr1[2][2];   // B half-0 / half-1 fragments

  // prologue: stage kt0 -> buf0, kt1 -> buf1; retire kt0; pre-read A0,B0
  STAGE_A(0,0,0); STAGE_B(0,0,0); STAGE_B(1,0,0); STAGE_A(1,0,0);
  STAGE_A(0,1,1); STAGE_B(0,1,1); STAGE_B(1,1,1); STAGE_A(1,1,1);
  asm volatile("s_waitcnt vmcnt(8)" ::: "memory");
  __builtin_amdgcn_s_barrier();
  READ_AF(afr0, 0, 0)
  READ_BF(bfr0, 0, 0)
  __builtin_amdgcn_sched_barrier(0);

#pragma unroll 1
  for (int kt = 0; kt < KT-2; kt += 2) {
    KTILE(kt,   0, 1, 1, "8", 1)
    KTILE(kt+1, 1, 0, 1, "8", 1)
  }
  // drain: tiles KT-2 (buf0) and KT-1 (buf1), no staging
  KTILE(KT-2, 0, 1, 0, "0", 1)
  KTILE(KT-1, 1, 0, 0, "0", 0)

  // epilogue
  int rq = (lane >> 4) * 4;
  int lc = lane & 15;
  if (GELU) {
    unsigned short* H = (unsigned short*)Cout;
#pragma unroll
    for (int mh = 0; mh < 2; mh++)
#pragma unroll
      for (int mi = 0; mi < 4; mi++)
#pragma unroll
        for (int j = 0; j < 4; j++) {
          int sl = rt*256 + mh*128 + wr*64 + mi*16 + rq + j;
          if (sl < n_e) {
            size_t hrow = (size_t)(off + sl) * NDIM;
#pragma unroll
            for (int nh = 0; nh < 2; nh++)
#pragma unroll
              for (int ni = 0; ni < 2; ni++) {
                int col = nt*256 + nh*128 + wc*32 + ni*16 + lc;
                float v = acc[mh*4+mi][nh*2+ni][j] + bias[e*NDIM + col];
                float g = 0.5f * v * (1.0f + erff(v * 0.70710678118654752f));
                H[hrow + col] = f2bf(g);
              }
          }
        }
  } else {
    float* Y = (float*)Cout;
#pragma unroll
    for (int mh = 0; mh < 2; mh++)
#pragma unroll
      for (int mi = 0; mi < 4; mi++)
#pragma unroll
        for (int j = 0; j < 4; j++) {
          int sl = rt*256 + mh*128 + wr*64 + mi*16 + rq + j;
          if (sl < n_e) {
            size_t yrow = (size_t)(off + sl) * NDIM;
#pragma unroll
            for (int nh = 0; nh < 2; nh++)
#pragma unroll
              for (int ni = 0; ni < 2; ni++) {
                int col = nt*256 + nh*128 + wc*32 + ni*16 + lc;
                Y[yrow + col] = acc[mh*4+mi][nh*2+ni][j];
              }
          }
        }
  }
}

// ---------- combine: out[t] = sum_k w_k * (Y[slot_k] + b2[e_k]) ----------
__global__ __launch_bounds__(256) void combine_kernel(
    const float* __restrict__ Y, const float* __restrict__ b2,
    const int* __restrict__ topi, const float* __restrict__ topw,
    const int* __restrict__ islot, float* __restrict__ out)
{
  int t = blockIdx.x;
  int s0 = islot[t*2], s1 = islot[t*2+1];
  int e0 = topi[t*2],  e1 = topi[t*2+1];
  float w0 = topw[t*2], w1 = topw[t*2+1];
  int d = threadIdx.x * 4;
  f4v y0 = *(const f4v*)(Y + (size_t)s0*DDIM + d);
  f4v y1 = *(const f4v*)(Y + (size_t)s1*DDIM + d);
  f4v c0 = *(const f4v*)(b2 + (size_t)e0*DDIM + d);
  f4v c1 = *(const f4v*)(b2 + (size_t)e1*DDIM + d);
  f4v o = w0*(y0+c0) + w1*(y1+c1);
  *(f4v*)(out + (size_t)t*DDIM + d) = o;
}

extern "C" void kernel_launch(void* const* d_in, const int* in_sizes, int n_in,
                              void* d_out, int out_size, void* d_ws, size_t ws_size,
                              hipStream_t stream) {
  const float* x  = (const float*)d_in[0];
  const float* w1 = (const float*)d_in[1];
  const float* b1 = (const float*)d_in[2];
  const float* w2 = (const float*)d_in[3];
  const float* b2 = (const float*)d_in[4];
  const float* rw = (const float*)d_in[5];
  const float* rb = (const float*)d_in[6];
  float* out = (float*)d_out;

  char* p = (char*)d_ws;
  size_t o = 0;
  auto take = [&](size_t bytes) -> void* {
    void* r = p + o;
    o = (o + bytes + 255) & ~(size_t)255;
    return r;
  };
  int*            counts  = (int*)take(NEXP * 4);
  int*            offsets = (int*)take((NEXP + 1) * 4);
  int*            topi    = (int*)take((size_t)NASG * 4);
  float*          topw    = (float*)take((size_t)NASG * 4);
  int*            perm    = (int*)take((size_t)NASG * 4);
  int*            islot   = (int*)take((size_t)NASG * 4);
  unsigned short* w1t     = (unsigned short*)take((size_t)NEXP * FDIM * DDIM * 2);
  unsigned short* xb      = (unsigned short*)take((size_t)TTOK * DDIM * 2);
  unsigned short* w2t     = (unsigned short*)take((size_t)NEXP * DDIM * FDIM * 2);
  unsigned short* H       = (unsigned short*)take((size_t)NASG * FDIM * 2);
  // Y aliases w1t (dead after gemm1): NASG*DDIM*4 = 64 MiB = exactly w1t's size
  float*          Y       = (float*)w1t;

  if (o > ws_size) {   // workspace insufficient: fail visibly (zeros)
    hipMemsetAsync(d_out, 0, (size_t)out_size * 4, stream);
    return;
  }

  hipMemsetAsync(counts, 0, NEXP * 4, stream);

  router_kernel<<<TTOK/4, 256, 0, stream>>>(x, rw, rb, topi, topw, counts, xb);
  permbuild_kernel<<<1, 256, 0, stream>>>(topi, counts, offsets, perm, islot);
  transpose_kernel<<<NEXP*(DDIM/64)*(FDIM/64), 256, 0, stream>>>(w1, w1t, DDIM, FDIM);
  transpose_kernel<<<NEXP*(FDIM/64)*(DDIM/64), 256, 0, stream>>>(w2, w2t, FDIM, DDIM);
  gemm256<DDIM, FDIM, true ><<<NEXP*MAXMT*(FDIM/256), 512, 0, stream>>>(xb, w1t, b1, perm, offsets, (void*)H);
  gemm256<FDIM, DDIM, false><<<NEXP*MAXMT*(DDIM/256), 512, 0, stream>>>(H, w2t, nullptr, nullptr, offsets, (void*)Y);
  combine_kernel<<<TTOK, 256, 0, stream>>>(Y, b2, topi, topw, islot, out);
}

// Round 9
// 810.161 us; speedup vs baseline: 1.8992x; 1.8510x over previous
//
#include <hip/hip_runtime.h>
#include <stdint.h>
#include <math.h>

#define TTOK 8192
#define DDIM 1024
#define FDIM 4096
#define NEXP 8
#define NASG (TTOK*2)
#define MAXMT 32   // max 256-row tiles per expert (worst case: all tokens on one expert)

typedef __attribute__((ext_vector_type(8))) short bf16x8;
typedef __attribute__((ext_vector_type(4))) float f32x4;
typedef __attribute__((ext_vector_type(4))) float f4v;
typedef __attribute__((ext_vector_type(8))) unsigned short u16x8;

__device__ __forceinline__ unsigned short f2bf(float f) {
  union { float f; unsigned int u; } v; v.f = f;
  unsigned int u = v.u;
  u += 0x7fffu + ((u >> 16) & 1u);   // round-to-nearest-even
  return (unsigned short)(u >> 16);
}

__device__ __forceinline__ void gload16(const void* g, void* l) {
  __builtin_amdgcn_global_load_lds(
    (__attribute__((address_space(1))) unsigned int*)(uintptr_t)g,
    (__attribute__((address_space(3))) unsigned int*)(uintptr_t)l,
    16, 0, 0);
}

// ------ router: one wave per token, fp64 accumulate; also emits xb (bf16) ------
__global__ __launch_bounds__(256) void router_kernel(
    const float* __restrict__ x, const float* __restrict__ rw,
    const float* __restrict__ rb, int* __restrict__ topi,
    float* __restrict__ topw, int* __restrict__ counts,
    unsigned short* __restrict__ xb)
{
  int wave = threadIdx.x >> 6;
  int lane = threadIdx.x & 63;
  int t = blockIdx.x * 4 + wave;
  if (t >= TTOK) return;
  double acc[8];
#pragma unroll
  for (int e = 0; e < 8; e++) acc[e] = 0.0;
  const float* xr = x + (size_t)t * DDIM;
  unsigned short* xbr = xb + (size_t)t * DDIM;
  for (int d = lane; d < DDIM; d += 64) {
    float xf = xr[d];
    xbr[d] = f2bf(xf);
    double xv = (double)xf;
    const float* rwr = rw + (size_t)d * 8;
#pragma unroll
    for (int e = 0; e < 8; e++) acc[e] += xv * (double)rwr[e];
  }
#pragma unroll
  for (int e = 0; e < 8; e++) {
    for (int off = 32; off >= 1; off >>= 1)
      acc[e] += __shfl_xor(acc[e], off);
  }
  if (lane == 0) {
    float lg[8];
#pragma unroll
    for (int e = 0; e < 8; e++) lg[e] = (float)acc[e] + rb[e];
    int i0 = 0;
    for (int e = 1; e < 8; e++) if (lg[e] > lg[i0]) i0 = e;   // ties -> lowest idx
    int i1 = -1;
    for (int e = 0; e < 8; e++) {
      if (e == i0) continue;
      if (i1 < 0 || lg[e] > lg[i1]) i1 = e;
    }
    double z = exp((double)lg[i1] - (double)lg[i0]);
    float w0 = (float)(1.0 / (1.0 + z));
    topi[t*2]   = i0;  topi[t*2+1] = i1;
    topw[t*2]   = w0;  topw[t*2+1] = 1.0f - w0;
    atomicAdd(&counts[i0], 1);
    atomicAdd(&counts[i1], 1);
  }
}

// ------ deterministic stable counting sort (single block; includes scan) ------
__global__ __launch_bounds__(256) void permbuild_kernel(
    const int* __restrict__ topi, const int* __restrict__ counts,
    int* __restrict__ offsets, int* __restrict__ perm, int* __restrict__ islot)
{
  __shared__ int hist[256 * 8];
  __shared__ int offs[NEXP + 1];
  int tid = threadIdx.x;
  if (tid == 0) {
    int s = 0;
    for (int e = 0; e < 8; e++) { offs[e] = s; s += counts[e]; }
    offs[8] = s;
    for (int e = 0; e <= 8; e++) offsets[e] = offs[e];
  }
  int cnt[8];
#pragma unroll
  for (int e = 0; e < 8; e++) cnt[e] = 0;
  int base = tid * 64;
  for (int i = 0; i < 64; i++) cnt[topi[base + i]]++;
#pragma unroll
  for (int e = 0; e < 8; e++) hist[tid*8 + e] = cnt[e];
  __syncthreads();
  if (tid < 8) {
    int s = 0;
    for (int th = 0; th < 256; th++) { int v = hist[th*8 + tid]; hist[th*8 + tid] = s; s += v; }
  }
  __syncthreads();
  int pos[8];
#pragma unroll
  for (int e = 0; e < 8; e++) pos[e] = offs[e] + hist[tid*8 + e];
  for (int i = 0; i < 64; i++) {
    int a = base + i;
    int e = topi[a];
    int p = pos[e]++;
    perm[p] = a >> 1;
    islot[a] = p;
  }
}

// ------- batched transpose + convert: [E][R][C] f32 -> [E][C][R] bf16 --------
__global__ __launch_bounds__(256) void transpose_kernel(
    const float* __restrict__ w, unsigned short* __restrict__ wt, int R, int C)
{
  __shared__ float tile[64][65];
  int tilesPerRow = C >> 6;
  int tilesPerMat = (R >> 6) * tilesPerRow;
  int b = blockIdx.x;
  int e = b / tilesPerMat;
  int rem = b - e * tilesPerMat;
  int tr = rem / tilesPerRow;
  int tc = rem - tr * tilesPerRow;
  int tid = threadIdx.x;
  size_t ibase = (size_t)e*R*C + ((size_t)tr*64)*C + (size_t)tc*64;
#pragma unroll
  for (int i = 0; i < 16; i++) {
    int idx = tid + i*256;
    int r = idx >> 6, c = idx & 63;
    tile[r][c] = w[ibase + (size_t)r*C + c];
  }
  __syncthreads();
  size_t obase = (size_t)e*R*C + ((size_t)tc*64)*R + (size_t)tr*64;
#pragma unroll
  for (int i = 0; i < 16; i++) {
    int idx = tid + i*256;
    int r = idx >> 6, c = idx & 63;
    wt[obase + (size_t)r*R + c] = f2bf(tile[c][r]);
  }
}

// ============ 256x256 grouped GEMM: m201-style 4-phase/K-tile schedule ========
// LDS 128KB = 8 x 16KB regions: A at (half*2+buf)*16KB; B at +64KB same.
// Per phase: {ds_read THIS quadrant's new operand, stage 1 half-tile, barrier,
// lgkmcnt(0), setprio, 16 MFMA, setprio, barrier}. Snake Q00->Q10->Q11->Q01
// (A0 re-read at P4 instead of holding 4 frag sets -> ~48 live frag VGPR, no
// spill). Stage schedule: P1:A0(t+1)->nbuf, P2:B0(t+2), P3:A1(t+2), P4:B1(t+2)
// (each 1 phase after that region's last read). vmcnt(6)=3 half-tiles in
// flight, once per K-tile at P4; drain vmcnt(0) at t>=KT-2.

#define READ_A(DST, MH, BUFV)                                                \
  { const char* Ab_ = ldsA + (((MH)*2+(BUFV))*16384);                        \
    _Pragma("unroll") for (int mi = 0; mi < 4; mi++) {                       \
      DST[mi][0] = *(const bf16x8*)(Ab_ + mi*2048 + aks0);                   \
      DST[mi][1] = *(const bf16x8*)(Ab_ + mi*2048 + aks1); } }

#define READ_B(DST, NH, BUFV)                                                \
  { const char* Bb_ = ldsB + (((NH)*2+(BUFV))*16384);                        \
    _Pragma("unroll") for (int ni = 0; ni < 2; ni++) {                       \
      DST[ni][0] = *(const bf16x8*)(Bb_ + ni*2048 + bks0);                   \
      DST[ni][1] = *(const bf16x8*)(Bb_ + ni*2048 + bks1); } }

#define STAGE_A(H_, T_, B_) { char* d_ = ldsA + (((H_)*2+(B_))*16384);       \
  gload16(srcA[H_][0] + (size_t)(T_)*128, d_ + dst0);                        \
  gload16(srcA[H_][1] + (size_t)(T_)*128, d_ + dst1); }

#define STAGE_B(H_, T_, B_) { char* d_ = ldsB + (((H_)*2+(B_))*16384);       \
  gload16(srcB[H_][0] + (size_t)(T_)*128, d_ + dst0);                        \
  gload16(srcB[H_][1] + (size_t)(T_)*128, d_ + dst1); }

#define MFMA_Q(MH, NH, A_, B_)                                               \
    __builtin_amdgcn_s_setprio(1);                                           \
    _Pragma("unroll") for (int ks = 0; ks < 2; ks++)                         \
      _Pragma("unroll") for (int mi = 0; mi < 4; mi++)                       \
        _Pragma("unroll") for (int ni = 0; ni < 2; ni++)                     \
          acc[(MH)*4+mi][(NH)*2+ni] = __builtin_amdgcn_mfma_f32_16x16x32_bf16( \
              A_[mi][ks], B_[ni][ks], acc[(MH)*4+mi][(NH)*2+ni], 0, 0, 0);   \
    __builtin_amdgcn_s_setprio(0);

#define PHASE_SYNC                                                           \
    __builtin_amdgcn_sched_barrier(0);                                       \
    __builtin_amdgcn_s_barrier();                                            \
    asm volatile("s_waitcnt lgkmcnt(0)" ::: "memory");                       \
    __builtin_amdgcn_sched_barrier(0);

template<int KDIM, int NDIM, bool GELU>
__global__ __launch_bounds__(512, 2) void gemm256(
    const unsigned short* __restrict__ Asrc,
    const unsigned short* __restrict__ Bsrc,
    const float* __restrict__ bias,
    const int* __restrict__ perm,
    const int* __restrict__ offsets,
    void* __restrict__ Cout)
{
  constexpr int KT = KDIM / 64;
  constexpr int NT = NDIM / 256;
  int b = blockIdx.x;
  int e = b / (MAXMT * NT);
  int rem = b - e * (MAXMT * NT);
  int rt = rem / NT;
  int nt = rem - rt * NT;
  int off = offsets[e];
  int n_e = offsets[e+1] - off;
  if (rt * 256 >= n_e) return;

  __shared__ __align__(16) unsigned short lds[2*2*2*8192];   // 128 KiB
  char* ldsA = (char*)lds;            // 4 A regions (half*2+buf)*16KB
  char* ldsB = (char*)lds + 65536;    // 4 B regions

  int tid = threadIdx.x;
  int lane = tid & 63;
  int wid = tid >> 6;
  int wr = wid >> 2;          // 0..1  (M strips)
  int wc = wid & 3;           // 0..3  (N strips)
  int rA  = wr*64 + (lane & 15);
  int rB  = wc*32 + (lane & 15);
  int tb0 = (lane >> 4) * 16;

  // per-thread read offsets within a region (swizzle XOR folded; (row&7) is
  // invariant across mi/ni since fragment row stride 16 = 0 mod 8)
  int xa  = (rA & 7) << 4;
  int xbw = (rB & 7) << 4;
  int aks0 = rA*128 + ( tb0       ^ xa);
  int aks1 = rA*128 + ((64 + tb0) ^ xa);
  int bks0 = rB*128 + ( tb0       ^ xbw);
  int bks1 = rB*128 + ((64 + tb0) ^ xbw);

  // per-thread stage pointers (inverse-swizzled global source, linear LDS dest)
  // A rows perm-gathered: independent lookup per (half, row-group)
  const char* srcA[2][2];
  const char* srcB[2][2];
#pragma unroll
  for (int h = 0; h < 2; h++) {
#pragma unroll
    for (int i = 0; i < 2; i++) {
      int slot = tid + i*512;
      int r = slot >> 3;
      int kc = (slot & 7) ^ (r & 7);
      int g = off + rt*256 + h*128 + r;
      if (g > NASG-1) g = NASG-1;
      size_t arow = GELU ? (size_t)perm[g] : (size_t)g;
      srcA[h][i] = (const char*)Asrc + (arow * KDIM + (size_t)kc*8) * 2;
      int col = nt*256 + h*128 + r;
      srcB[h][i] = (const char*)Bsrc + (((size_t)e*NDIM + col) * KDIM + (size_t)kc*8) * 2;
    }
  }
  int dst0 = tid*16;
  int dst1 = tid*16 + 8192;

  f32x4 acc[8][4];
#pragma unroll
  for (int m = 0; m < 8; m++)
#pragma unroll
    for (int n = 0; n < 4; n++) acc[m][n] = (f32x4){0.f,0.f,0.f,0.f};

  bf16x8 af[4][2];    // current A quadrant fragments (rewritten each phase)
  bf16x8 bf_[2][2];   // current B fragments (held at most 2 phases)

  // prologue: tile0 fully (buf0, 8 loads) then B0,A1,B1 of tile1 (buf1, 6).
  // vmcnt(6) retires tile0; A0(1) staged inside tile0's P1.
  STAGE_A(0,0,0); STAGE_B(0,0,0); STAGE_A(1,0,0); STAGE_B(1,0,0);
  STAGE_B(0,1,1); STAGE_A(1,1,1); STAGE_B(1,1,1);
  asm volatile("s_waitcnt vmcnt(6)" ::: "memory");
  __builtin_amdgcn_s_barrier();

#pragma unroll 1
  for (int t = 0; t < KT; ++t) {
    int buf = t & 1;
    int nbuf = buf ^ 1;
    // P1: Q(0,0) — read A0+B0 (12); stage A0(t+1) -> nbuf
    READ_A(af, 0, buf)
    READ_B(bf_, 0, buf)
    if (t+1 < KT) STAGE_A(0, t+1, nbuf);
    asm volatile("s_waitcnt lgkmcnt(8)" ::: "memory");
    PHASE_SYNC
    MFMA_Q(0,0, af, bf_)
    __builtin_amdgcn_s_barrier();
    // P2: Q(1,0) — read A1 (8), reuse B0 regs; stage B0(t+2) -> buf
    READ_A(af, 1, buf)
    if (t+2 < KT) STAGE_B(0, t+2, buf);
    PHASE_SYNC
    MFMA_Q(1,0, af, bf_)
    __builtin_amdgcn_s_barrier();
    // P3: Q(1,1) — read B1 (4), reuse A1 regs; stage A1(t+2) -> buf
    READ_B(bf_, 1, buf)
    if (t+2 < KT) STAGE_A(1, t+2, buf);
    PHASE_SYNC
    MFMA_Q(1,1, af, bf_)
    __builtin_amdgcn_s_barrier();
    // P4: Q(0,1) — re-read A0 (8), reuse B1 regs; stage B1(t+2) -> buf;
    // single counted vmcnt per K-tile
    READ_A(af, 0, buf)
    if (t+2 < KT) STAGE_B(1, t+2, buf);
    PHASE_SYNC
    MFMA_Q(0,1, af, bf_)
    if (t < KT-2) { asm volatile("s_waitcnt vmcnt(6)" ::: "memory"); }
    else          { asm volatile("s_waitcnt vmcnt(0)" ::: "memory"); }
    __builtin_amdgcn_s_barrier();
  }

  // epilogue
  int rq = (lane >> 4) * 4;
  int lc = lane & 15;
  if (GELU) {
    unsigned short* H = (unsigned short*)Cout;
#pragma unroll
    for (int mh = 0; mh < 2; mh++)
#pragma unroll
      for (int mi = 0; mi < 4; mi++)
#pragma unroll
        for (int j = 0; j < 4; j++) {
          int sl = rt*256 + mh*128 + wr*64 + mi*16 + rq + j;
          if (sl < n_e) {
            size_t hrow = (size_t)(off + sl) * NDIM;
#pragma unroll
            for (int nh = 0; nh < 2; nh++)
#pragma unroll
              for (int ni = 0; ni < 2; ni++) {
                int col = nt*256 + nh*128 + wc*32 + ni*16 + lc;
                float v = acc[mh*4+mi][nh*2+ni][j] + bias[e*NDIM + col];
                float g = 0.5f * v * (1.0f + erff(v * 0.70710678118654752f));
                H[hrow + col] = f2bf(g);
              }
          }
        }
  } else {
    float* Y = (float*)Cout;
#pragma unroll
    for (int mh = 0; mh < 2; mh++)
#pragma unroll
      for (int mi = 0; mi < 4; mi++)
#pragma unroll
        for (int j = 0; j < 4; j++) {
          int sl = rt*256 + mh*128 + wr*64 + mi*16 + rq + j;
          if (sl < n_e) {
            size_t yrow = (size_t)(off + sl) * NDIM;
#pragma unroll
            for (int nh = 0; nh < 2; nh++)
#pragma unroll
              for (int ni = 0; ni < 2; ni++) {
                int col = nt*256 + nh*128 + wc*32 + ni*16 + lc;
                Y[yrow + col] = acc[mh*4+mi][nh*2+ni][j];
              }
          }
        }
  }
}

// ---------- combine: out[t] = sum_k w_k * (Y[slot_k] + b2[e_k]) ----------
__global__ __launch_bounds__(256) void combine_kernel(
    const float* __restrict__ Y, const float* __restrict__ b2,
    const int* __restrict__ topi, const float* __restrict__ topw,
    const int* __restrict__ islot, float* __restrict__ out)
{
  int t = blockIdx.x;
  int s0 = islot[t*2], s1 = islot[t*2+1];
  int e0 = topi[t*2],  e1 = topi[t*2+1];
  float w0 = topw[t*2], w1 = topw[t*2+1];
  int d = threadIdx.x * 4;
  f4v y0 = *(const f4v*)(Y + (size_t)s0*DDIM + d);
  f4v y1 = *(const f4v*)(Y + (size_t)s1*DDIM + d);
  f4v c0 = *(const f4v*)(b2 + (size_t)e0*DDIM + d);
  f4v c1 = *(const f4v*)(b2 + (size_t)e1*DDIM + d);
  f4v o = w0*(y0+c0) + w1*(y1+c1);
  *(f4v*)(out + (size_t)t*DDIM + d) = o;
}

extern "C" void kernel_launch(void* const* d_in, const int* in_sizes, int n_in,
                              void* d_out, int out_size, void* d_ws, size_t ws_size,
                              hipStream_t stream) {
  const float* x  = (const float*)d_in[0];
  const float* w1 = (const float*)d_in[1];
  const float* b1 = (const float*)d_in[2];
  const float* w2 = (const float*)d_in[3];
  const float* b2 = (const float*)d_in[4];
  const float* rw = (const float*)d_in[5];
  const float* rb = (const float*)d_in[6];
  float* out = (float*)d_out;

  char* p = (char*)d_ws;
  size_t o = 0;
  auto take = [&](size_t bytes) -> void* {
    void* r = p + o;
    o = (o + bytes + 255) & ~(size_t)255;
    return r;
  };
  int*            counts  = (int*)take(NEXP * 4);
  int*            offsets = (int*)take((NEXP + 1) * 4);
  int*            topi    = (int*)take((size_t)NASG * 4);
  float*          topw    = (float*)take((size_t)NASG * 4);
  int*            perm    = (int*)take((size_t)NASG * 4);
  int*            islot   = (int*)take((size_t)NASG * 4);
  unsigned short* w1t     = (unsigned short*)take((size_t)NEXP * FDIM * DDIM * 2);
  unsigned short* xb      = (unsigned short*)take((size_t)TTOK * DDIM * 2);
  unsigned short* w2t     = (unsigned short*)take((size_t)NEXP * DDIM * FDIM * 2);
  unsigned short* H       = (unsigned short*)take((size_t)NASG * FDIM * 2);
  // Y aliases w1t (dead after gemm1): NASG*DDIM*4 = 64 MiB = exactly w1t's size
  float*          Y       = (float*)w1t;

  if (o > ws_size) {   // workspace insufficient: fail visibly (zeros)
    hipMemsetAsync(d_out, 0, (size_t)out_size * 4, stream);
    return;
  }

  hipMemsetAsync(counts, 0, NEXP * 4, stream);

  router_kernel<<<TTOK/4, 256, 0, stream>>>(x, rw, rb, topi, topw, counts, xb);
  permbuild_kernel<<<1, 256, 0, stream>>>(topi, counts, offsets, perm, islot);
  transpose_kernel<<<NEXP*(DDIM/64)*(FDIM/64), 256, 0, stream>>>(w1, w1t, DDIM, FDIM);
  transpose_kernel<<<NEXP*(FDIM/64)*(DDIM/64), 256, 0, stream>>>(w2, w2t, FDIM, DDIM);
  gemm256<DDIM, FDIM, true ><<<NEXP*MAXMT*(FDIM/256), 512, 0, stream>>>(xb, w1t, b1, perm, offsets, (void*)H);
  gemm256<FDIM, DDIM, false><<<NEXP*MAXMT*(DDIM/256), 512, 0, stream>>>(H, w2t, nullptr, nullptr, offsets, (void*)Y);
  combine_kernel<<<TTOK, 256, 0, stream>>>(Y, b2, topi, topw, islot, out);
}

// Round 10
// 757.267 us; speedup vs baseline: 2.0319x; 1.0698x over previous
//
#include <hip/hip_runtime.h>
#include <stdint.h>
#include <math.h>

#define TTOK 8192
#define DDIM 1024
#define FDIM 4096
#define NEXP 8
#define NASG (TTOK*2)
#define MT128 64   // max 128-row tiles per expert (8192 tokens / 128)

typedef __attribute__((ext_vector_type(8))) short bf16x8;
typedef __attribute__((ext_vector_type(4))) float f32x4;
typedef __attribute__((ext_vector_type(4))) float f4v;
typedef __attribute__((ext_vector_type(8))) unsigned short u16x8;

__device__ __forceinline__ unsigned short f2bf(float f) {
  union { float f; unsigned int u; } v; v.f = f;
  unsigned int u = v.u;
  u += 0x7fffu + ((u >> 16) & 1u);   // round-to-nearest-even
  return (unsigned short)(u >> 16);
}

__device__ __forceinline__ void gload16(const void* g, void* l) {
  __builtin_amdgcn_global_load_lds(
    (__attribute__((address_space(1))) unsigned int*)(uintptr_t)g,
    (__attribute__((address_space(3))) unsigned int*)(uintptr_t)l,
    16, 0, 0);
}

// ------ router: one wave per token, fp64 accumulate; also emits xb (bf16) ------
__global__ __launch_bounds__(256) void router_kernel(
    const float* __restrict__ x, const float* __restrict__ rw,
    const float* __restrict__ rb, int* __restrict__ topi,
    float* __restrict__ topw, int* __restrict__ counts,
    unsigned short* __restrict__ xb)
{
  int wave = threadIdx.x >> 6;
  int lane = threadIdx.x & 63;
  int t = blockIdx.x * 4 + wave;
  if (t >= TTOK) return;
  double acc[8];
#pragma unroll
  for (int e = 0; e < 8; e++) acc[e] = 0.0;
  const float* xr = x + (size_t)t * DDIM;
  unsigned short* xbr = xb + (size_t)t * DDIM;
  for (int d = lane; d < DDIM; d += 64) {
    float xf = xr[d];
    xbr[d] = f2bf(xf);
    double xv = (double)xf;
    const float* rwr = rw + (size_t)d * 8;
#pragma unroll
    for (int e = 0; e < 8; e++) acc[e] += xv * (double)rwr[e];
  }
#pragma unroll
  for (int e = 0; e < 8; e++) {
    for (int off = 32; off >= 1; off >>= 1)
      acc[e] += __shfl_xor(acc[e], off);
  }
  if (lane == 0) {
    float lg[8];
#pragma unroll
    for (int e = 0; e < 8; e++) lg[e] = (float)acc[e] + rb[e];
    int i0 = 0;
    for (int e = 1; e < 8; e++) if (lg[e] > lg[i0]) i0 = e;   // ties -> lowest idx
    int i1 = -1;
    for (int e = 0; e < 8; e++) {
      if (e == i0) continue;
      if (i1 < 0 || lg[e] > lg[i1]) i1 = e;
    }
    double z = exp((double)lg[i1] - (double)lg[i0]);
    float w0 = (float)(1.0 / (1.0 + z));
    topi[t*2]   = i0;  topi[t*2+1] = i1;
    topw[t*2]   = w0;  topw[t*2+1] = 1.0f - w0;
    atomicAdd(&counts[i0], 1);
    atomicAdd(&counts[i1], 1);
  }
}

// ------ deterministic stable counting sort (single block; includes scan) ------
__global__ __launch_bounds__(256) void permbuild_kernel(
    const int* __restrict__ topi, const int* __restrict__ counts,
    int* __restrict__ offsets, int* __restrict__ perm, int* __restrict__ islot)
{
  __shared__ int hist[256 * 8];
  __shared__ int offs[NEXP + 1];
  int tid = threadIdx.x;
  if (tid == 0) {
    int s = 0;
    for (int e = 0; e < 8; e++) { offs[e] = s; s += counts[e]; }
    offs[8] = s;
    for (int e = 0; e <= 8; e++) offsets[e] = offs[e];
  }
  int cnt[8];
#pragma unroll
  for (int e = 0; e < 8; e++) cnt[e] = 0;
  int base = tid * 64;
  for (int i = 0; i < 64; i++) cnt[topi[base + i]]++;
#pragma unroll
  for (int e = 0; e < 8; e++) hist[tid*8 + e] = cnt[e];
  __syncthreads();
  if (tid < 8) {
    int s = 0;
    for (int th = 0; th < 256; th++) { int v = hist[th*8 + tid]; hist[th*8 + tid] = s; s += v; }
  }
  __syncthreads();
  int pos[8];
#pragma unroll
  for (int e = 0; e < 8; e++) pos[e] = offs[e] + hist[tid*8 + e];
  for (int i = 0; i < 64; i++) {
    int a = base + i;
    int e = topi[a];
    int p = pos[e]++;
    perm[p] = a >> 1;
    islot[a] = p;
  }
}

// ------- batched transpose + convert: [E][R][C] f32 -> [E][C][R] bf16 --------
__global__ __launch_bounds__(256) void transpose_kernel(
    const float* __restrict__ w, unsigned short* __restrict__ wt, int R, int C)
{
  __shared__ float tile[64][65];
  int tilesPerRow = C >> 6;
  int tilesPerMat = (R >> 6) * tilesPerRow;
  int b = blockIdx.x;
  int e = b / tilesPerMat;
  int rem = b - e * tilesPerMat;
  int tr = rem / tilesPerRow;
  int tc = rem - tr * tilesPerRow;
  int tid = threadIdx.x;
  size_t ibase = (size_t)e*R*C + ((size_t)tr*64)*C + (size_t)tc*64;
#pragma unroll
  for (int i = 0; i < 16; i++) {
    int idx = tid + i*256;
    int r = idx >> 6, c = idx & 63;
    tile[r][c] = w[ibase + (size_t)r*C + c];
  }
  __syncthreads();
  size_t obase = (size_t)e*R*C + ((size_t)tc*64)*R + (size_t)tr*64;
#pragma unroll
  for (int i = 0; i < 16; i++) {
    int idx = tid + i*256;
    int r = idx >> 6, c = idx & 63;
    wt[obase + (size_t)r*R + c] = f2bf(tile[c][r]);
  }
}

// ========= 128x128 grouped GEMM, m97-faithful (multi-block overlap) ==========
// 256 threads (4 waves, 2x2), per-wave 64x64 output. BK=64. LDS 32KB single
// buffer (A 16KB + B 16KB), 2 __syncthreads per K-step (compiler inserts the
// vmcnt/lgkm drains -- proven m97 structure; ~3 blocks/CU hide the stalls).
// Swizzle byte ^= (row&7)<<4: inverse on per-lane global src, fwd on ds reads.

template<int KDIM, int NDIM, bool GELU>
__global__ void gemm128(
    const unsigned short* __restrict__ Asrc,
    const unsigned short* __restrict__ Bsrc,
    const float* __restrict__ bias,
    const int* __restrict__ perm,
    const int* __restrict__ offsets,
    void* __restrict__ Cout)
{
  constexpr int KT = KDIM / 64;
  constexpr int NT = NDIM / 128;
  int b = blockIdx.x;
  int e = b / (MT128 * NT);
  int rem = b - e * (MT128 * NT);
  int rt = rem / NT;
  int nt = rem - rt * NT;
  int off = offsets[e];
  int n_e = offsets[e+1] - off;
  if (rt * 128 >= n_e) return;

  __shared__ __align__(16) unsigned short lds[2 * 128 * 64];   // 32 KiB
  char* ldsA = (char*)lds;            // A: 128 rows x 128B
  char* ldsB = (char*)lds + 16384;    // B: 128 rows x 128B

  int tid = threadIdx.x;
  int lane = tid & 63;
  int wid = tid >> 6;          // 0..3
  int wr = wid >> 1;           // 0..1 (M strip)
  int wc = wid & 1;            // 0..1 (N strip)
  int tb0 = (lane >> 4) * 16;
  int rA = wr*64 + (lane & 15);
  int rB = wc*64 + (lane & 15);
  int xa  = (rA & 7) << 4;
  int xbw = (rB & 7) << 4;
  int aks0 = rA*128 + ( tb0       ^ xa);
  int aks1 = rA*128 + ((64 + tb0) ^ xa);
  int bks0 = rB*128 + ( tb0       ^ xbw);
  int bks1 = rB*128 + ((64 + tb0) ^ xbw);

  // staging: 4 A-slots + 4 B-slots per thread (1024 slots = 128 rows x 8 chunks)
  const char* srcA[4];
  const char* srcB[4];
#pragma unroll
  for (int i = 0; i < 4; i++) {
    int slot = tid + i*256;
    int r = slot >> 3;
    int kc = (slot & 7) ^ (r & 7);   // inverse swizzle on global k-chunk
    int g = off + rt*128 + r;
    if (g > NASG-1) g = NASG-1;
    size_t ar = GELU ? (size_t)perm[g] : (size_t)g;
    srcA[i] = (const char*)Asrc + (ar * KDIM + (size_t)kc*8) * 2;
    int col = nt*128 + r;
    srcB[i] = (const char*)Bsrc + (((size_t)e*NDIM + col) * KDIM + (size_t)kc*8) * 2;
  }
  int dstOff = tid * 16;

  f32x4 acc[4][4];
#pragma unroll
  for (int m = 0; m < 4; m++)
#pragma unroll
    for (int n = 0; n < 4; n++) acc[m][n] = (f32x4){0.f,0.f,0.f,0.f};

#pragma unroll 1
  for (int kt = 0; kt < KT; ++kt) {
    __syncthreads();   // previous compute done before overwrite
#pragma unroll
    for (int i = 0; i < 4; i++) {
      gload16(srcA[i] + (size_t)kt*128, ldsA + dstOff + i*4096);
      gload16(srcB[i] + (size_t)kt*128, ldsB + dstOff + i*4096);
    }
    __syncthreads();   // compiler-inserted vmcnt(0) drain: tile ready
#pragma unroll
    for (int ks = 0; ks < 2; ks++) {
      int ao = ks ? aks1 : aks0;
      int bo = ks ? bks1 : bks0;
      bf16x8 a[4], bb[4];
#pragma unroll
      for (int mi = 0; mi < 4; mi++) a[mi]  = *(const bf16x8*)(ldsA + mi*2048 + ao);
#pragma unroll
      for (int ni = 0; ni < 4; ni++) bb[ni] = *(const bf16x8*)(ldsB + ni*2048 + bo);
#pragma unroll
      for (int mi = 0; mi < 4; mi++)
#pragma unroll
        for (int ni = 0; ni < 4; ni++)
          acc[mi][ni] = __builtin_amdgcn_mfma_f32_16x16x32_bf16(a[mi], bb[ni], acc[mi][ni], 0, 0, 0);
    }
  }

  // epilogue
  int rq = (lane >> 4) * 4;
  int lc = lane & 15;
  if (GELU) {
    unsigned short* H = (unsigned short*)Cout;
#pragma unroll
    for (int mi = 0; mi < 4; mi++)
#pragma unroll
      for (int j = 0; j < 4; j++) {
        int sl = rt*128 + wr*64 + mi*16 + rq + j;
        if (sl < n_e) {
          size_t hrow = (size_t)(off + sl) * NDIM;
#pragma unroll
          for (int ni = 0; ni < 4; ni++) {
            int col = nt*128 + wc*64 + ni*16 + lc;
            float v = acc[mi][ni][j] + bias[e*NDIM + col];
            float g = 0.5f * v * (1.0f + erff(v * 0.70710678118654752f));
            H[hrow + col] = f2bf(g);
          }
        }
      }
  } else {
    float* Y = (float*)Cout;
#pragma unroll
    for (int mi = 0; mi < 4; mi++)
#pragma unroll
      for (int j = 0; j < 4; j++) {
        int sl = rt*128 + wr*64 + mi*16 + rq + j;
        if (sl < n_e) {
          size_t yrow = (size_t)(off + sl) * NDIM;
#pragma unroll
          for (int ni = 0; ni < 4; ni++) {
            int col = nt*128 + wc*64 + ni*16 + lc;
            Y[yrow + col] = acc[mi][ni][j];
          }
        }
      }
  }
}

// ---------- combine: out[t] = sum_k w_k * (Y[slot_k] + b2[e_k]) ----------
__global__ __launch_bounds__(256) void combine_kernel(
    const float* __restrict__ Y, const float* __restrict__ b2,
    const int* __restrict__ topi, const float* __restrict__ topw,
    const int* __restrict__ islot, float* __restrict__ out)
{
  int t = blockIdx.x;
  int s0 = islot[t*2], s1 = islot[t*2+1];
  int e0 = topi[t*2],  e1 = topi[t*2+1];
  float w0 = topw[t*2], w1 = topw[t*2+1];
  int d = threadIdx.x * 4;
  f4v y0 = *(const f4v*)(Y + (size_t)s0*DDIM + d);
  f4v y1 = *(const f4v*)(Y + (size_t)s1*DDIM + d);
  f4v c0 = *(const f4v*)(b2 + (size_t)e0*DDIM + d);
  f4v c1 = *(const f4v*)(b2 + (size_t)e1*DDIM + d);
  f4v o = w0*(y0+c0) + w1*(y1+c1);
  *(f4v*)(out + (size_t)t*DDIM + d) = o;
}

extern "C" void kernel_launch(void* const* d_in, const int* in_sizes, int n_in,
                              void* d_out, int out_size, void* d_ws, size_t ws_size,
                              hipStream_t stream) {
  const float* x  = (const float*)d_in[0];
  const float* w1 = (const float*)d_in[1];
  const float* b1 = (const float*)d_in[2];
  const float* w2 = (const float*)d_in[3];
  const float* b2 = (const float*)d_in[4];
  const float* rw = (const float*)d_in[5];
  const float* rb = (const float*)d_in[6];
  float* out = (float*)d_out;

  char* p = (char*)d_ws;
  size_t o = 0;
  auto take = [&](size_t bytes) -> void* {
    void* r = p + o;
    o = (o + bytes + 255) & ~(size_t)255;
    return r;
  };
  int*            counts  = (int*)take(NEXP * 4);
  int*            offsets = (int*)take((NEXP + 1) * 4);
  int*            topi    = (int*)take((size_t)NASG * 4);
  float*          topw    = (float*)take((size_t)NASG * 4);
  int*            perm    = (int*)take((size_t)NASG * 4);
  int*            islot   = (int*)take((size_t)NASG * 4);
  unsigned short* w1t     = (unsigned short*)take((size_t)NEXP * FDIM * DDIM * 2);
  unsigned short* xb      = (unsigned short*)take((size_t)TTOK * DDIM * 2);
  unsigned short* w2t     = (unsigned short*)take((size_t)NEXP * DDIM * FDIM * 2);
  unsigned short* H       = (unsigned short*)take((size_t)NASG * FDIM * 2);
  // Y aliases w1t (dead after gemm1): NASG*DDIM*4 = 64 MiB = exactly w1t's size
  float*          Y       = (float*)w1t;

  if (o > ws_size) {   // workspace insufficient: fail visibly (zeros)
    hipMemsetAsync(d_out, 0, (size_t)out_size * 4, stream);
    return;
  }

  hipMemsetAsync(counts, 0, NEXP * 4, stream);

  router_kernel<<<TTOK/4, 256, 0, stream>>>(x, rw, rb, topi, topw, counts, xb);
  permbuild_kernel<<<1, 256, 0, stream>>>(topi, counts, offsets, perm, islot);
  transpose_kernel<<<NEXP*(DDIM/64)*(FDIM/64), 256, 0, stream>>>(w1, w1t, DDIM, FDIM);
  transpose_kernel<<<NEXP*(FDIM/64)*(DDIM/64), 256, 0, stream>>>(w2, w2t, FDIM, DDIM);
  gemm128<DDIM, FDIM, true ><<<NEXP*MT128*(FDIM/128), 256, 0, stream>>>(xb, w1t, b1, perm, offsets, (void*)H);
  gemm128<FDIM, DDIM, false><<<NEXP*MT128*(DDIM/128), 256, 0, stream>>>(H, w2t, nullptr, nullptr, offsets, (void*)Y);
  combine_kernel<<<TTOK, 256, 0, stream>>>(Y, b2, topi, topw, islot, out);
}